// Round 5
// baseline (1287.881 us; speedup 1.0000x reference)
//
#include <hip/hip_runtime.h>
#include <stdint.h>

// d_out (f32) layout: seed [64][3][256] @0, x3 [64][128][256] @49152,
// fps x [64][3][512] @2146304.  x3 region doubles as x1 staging.
#define X3_OFF 49152
#define FPS_OFF 2146304

// ws (f32) layout: T1 @0, T1s @8192, T3 @16384, T3s @24576 (each [128][64]),
// featT [512][64] @32768.  Total 65536 floats = 256 KB.

// ---------------------------------------------------------------------------
// k_prep: featT[c][b] = feat[b][c]
// ---------------------------------------------------------------------------
__global__ void k_prep(const float* __restrict__ feat, float* __restrict__ ws) {
    int g = blockIdx.x * 256 + threadIdx.x;   // 32768
    int c = g >> 6, b = g & 63;
    ws[32768 + c * 64 + b] = feat[b * 512 + c];
}

// ---------------------------------------------------------------------------
// k_tterms: T[o][b] = sum_c W[o][128+c] * feat[b][c] for the 4 concat weights
// (m1_w1, m1_ws, m3_w1, m3_ws; each [128][640], feat half = cols 128..639).
// ---------------------------------------------------------------------------
__global__ void k_tterms(const float* __restrict__ w1, const float* __restrict__ ws1,
                         const float* __restrict__ w3, const float* __restrict__ ws3,
                         float* __restrict__ ws) {
    int g = blockIdx.x * 256 + threadIdx.x;   // 32768
    int which = g >> 13;
    int o = (g >> 6) & 127;
    int b = g & 63;
    const float* W = (which == 0) ? w1 : (which == 1) ? ws1
                     : (which == 2) ? w3 : ws3;
    const float* ft = ws + 32768;
    float acc = 0.f;
    for (int c = 0; c < 512; ++c)
        acc = fmaf(W[o * 640 + 128 + c], ft[c * 64 + b], acc);
    ws[which * 8192 + o * 64 + b] = acc;
}

// ---------------------------------------------------------------------------
// k_deconv: x1[b][o][k] = sum_c feat[b][c]*ps_w[c][o][k] + ps_b[o]
// written f32 into the d_out x3 region (staging; later overwritten with x3).
// Thread owns n=(o,k) (coalesced psw); 16 batches/thread via uniform featT.
// ---------------------------------------------------------------------------
__global__ void k_deconv(const float* __restrict__ psw,
                         const float* __restrict__ psb,
                         const float* __restrict__ ws,
                         float* __restrict__ stage) {
    int n = blockIdx.x * 256 + threadIdx.x;   // 32768 = o*256+k
    int b0 = blockIdx.y * 16;
    const float* featT = ws + 32768;
    float acc[16];
    float bias = psb[n >> 8];
#pragma unroll
    for (int j = 0; j < 16; ++j) acc[j] = bias;
    for (int c = 0; c < 512; ++c) {
        float pw = psw[c * 32768 + n];
#pragma unroll
        for (int j = 0; j < 16; ++j)
            acc[j] = fmaf(pw, featT[c * 64 + b0 + j], acc[j]);
    }
#pragma unroll
    for (int j = 0; j < 16; ++j)
        stage[(b0 + j) * 32768 + n] = acc[j];
}

// ---------------------------------------------------------------------------
// gemm8: acc[r] += sum_i S[i][lane] * Wg[(o0+r)*ld + i]  (o0 wave-uniform)
// ---------------------------------------------------------------------------
__device__ __forceinline__ void gemm8(const float* __restrict__ Wg, int ld, int o0,
                                      const float* S, int K, float acc[8], int lane) {
#pragma unroll 4
    for (int i = 0; i < K; ++i) {
        float x = S[i * 64 + lane];
#pragma unroll
        for (int r = 0; r < 8; ++r)
            acc[r] = fmaf(x, Wg[(o0 + r) * ld + i], acc[r]);
    }
}

// ---------------------------------------------------------------------------
// k_fused: per (b, 64-wide k-tile): x1 -> m1 -> m2 -> m3 -> m4/seed.
// 512 threads = 8 waves; lane = point; wave owns output-channel rows.
// Activations ping-pong between two 32KB LDS buffers.
// ---------------------------------------------------------------------------
struct FusedW {
    const float *m1_w1, *m1_b1, *m1_w2, *m1_b2, *m1_ws, *m1_bs;
    const float *m2_w1, *m2_b1, *m2_w2, *m2_b2, *m2_ws, *m2_bs;
    const float *m3_w1, *m3_b1, *m3_w2, *m3_b2, *m3_ws, *m3_bs;
    const float *m4_w1, *m4_b1, *m4_w2, *m4_b2;
};

__global__ void __launch_bounds__(512)
k_fused(FusedW P, const float* __restrict__ ws, float* __restrict__ fout) {
    int b  = blockIdx.x >> 2;
    int k0 = (blockIdx.x & 3) * 64;
    int lane = threadIdx.x & 63;
    int wave = __builtin_amdgcn_readfirstlane(threadIdx.x >> 6);

    const float* T1  = ws;
    const float* T1s = ws + 8192;
    const float* T3  = ws + 16384;
    const float* T3s = ws + 24576;
    float* stage = fout + X3_OFF + b * 32768;   // this batch's x1/x3 region

    __shared__ float Xs[8192];   // [ch<=128][64]
    __shared__ float Hs[8192];

    // stage x1 tile into Xs
#pragma unroll
    for (int s = 0; s < 16; ++s) {
        int e = threadIdx.x + s * 512;          // e = o*64 + kk
        int o = e >> 6, kk = e & 63;
        Xs[e] = stage[o * 256 + k0 + kk];
    }
    __syncthreads();

    float yreg[2][8];

    // ================= m1 =================  (concat -> T1/T1s terms)
#pragma unroll
    for (int half = 0; half < 2; ++half) {
        int o0 = wave * 16 + half * 8;
        float acc[8];
#pragma unroll
        for (int r = 0; r < 8; ++r) acc[r] = T1[(o0 + r) * 64 + b] + P.m1_b1[o0 + r];
        gemm8(P.m1_w1, 640, o0, Xs, 128, acc, lane);
#pragma unroll
        for (int r = 0; r < 8; ++r) Hs[(o0 + r) * 64 + lane] = fmaxf(acc[r], 0.f);
    }
    __syncthreads();
#pragma unroll
    for (int half = 0; half < 2; ++half) {
        int o0 = wave * 16 + half * 8;
        float acc[8];
#pragma unroll
        for (int r = 0; r < 8; ++r)
            acc[r] = T1s[(o0 + r) * 64 + b] + P.m1_b2[o0 + r] + P.m1_bs[o0 + r];
        gemm8(P.m1_w2, 128, o0, Hs, 128, acc, lane);
        gemm8(P.m1_ws, 640, o0, Xs, 128, acc, lane);
#pragma unroll
        for (int r = 0; r < 8; ++r) yreg[half][r] = acc[r];
    }
    __syncthreads();
#pragma unroll
    for (int half = 0; half < 2; ++half) {
        int o0 = wave * 16 + half * 8;
#pragma unroll
        for (int r = 0; r < 8; ++r) Xs[(o0 + r) * 64 + lane] = yreg[half][r];
    }
    __syncthreads();

    // ================= m2 =================  (no concat)
    {
        int o0 = wave * 8;   // rows 0..63
        float acc[8];
#pragma unroll
        for (int r = 0; r < 8; ++r) acc[r] = P.m2_b1[o0 + r];
        gemm8(P.m2_w1, 128, o0, Xs, 128, acc, lane);
#pragma unroll
        for (int r = 0; r < 8; ++r) Hs[(o0 + r) * 64 + lane] = fmaxf(acc[r], 0.f);
    }
    __syncthreads();
#pragma unroll
    for (int half = 0; half < 2; ++half) {
        int o0 = wave * 16 + half * 8;
        float acc[8];
#pragma unroll
        for (int r = 0; r < 8; ++r) acc[r] = P.m2_b2[o0 + r] + P.m2_bs[o0 + r];
        gemm8(P.m2_w2, 64, o0, Hs, 64, acc, lane);
        gemm8(P.m2_ws, 128, o0, Xs, 128, acc, lane);
#pragma unroll
        for (int r = 0; r < 8; ++r) yreg[half][r] = acc[r];
    }
    __syncthreads();
#pragma unroll
    for (int half = 0; half < 2; ++half) {
        int o0 = wave * 16 + half * 8;
#pragma unroll
        for (int r = 0; r < 8; ++r) Xs[(o0 + r) * 64 + lane] = yreg[half][r];
    }
    __syncthreads();

    // ================= m3 =================  (concat -> T3/T3s terms)
#pragma unroll
    for (int half = 0; half < 2; ++half) {
        int o0 = wave * 16 + half * 8;
        float acc[8];
#pragma unroll
        for (int r = 0; r < 8; ++r) acc[r] = T3[(o0 + r) * 64 + b] + P.m3_b1[o0 + r];
        gemm8(P.m3_w1, 640, o0, Xs, 128, acc, lane);
#pragma unroll
        for (int r = 0; r < 8; ++r) Hs[(o0 + r) * 64 + lane] = fmaxf(acc[r], 0.f);
    }
    __syncthreads();
#pragma unroll
    for (int half = 0; half < 2; ++half) {
        int o0 = wave * 16 + half * 8;
        float acc[8];
#pragma unroll
        for (int r = 0; r < 8; ++r)
            acc[r] = T3s[(o0 + r) * 64 + b] + P.m3_b2[o0 + r] + P.m3_bs[o0 + r];
        gemm8(P.m3_w2, 128, o0, Hs, 128, acc, lane);
        gemm8(P.m3_ws, 640, o0, Xs, 128, acc, lane);
#pragma unroll
        for (int r = 0; r < 8; ++r) yreg[half][r] = acc[r];
    }
    __syncthreads();
#pragma unroll
    for (int half = 0; half < 2; ++half) {   // x3 -> Xs and -> d_out (f32)
        int o0 = wave * 16 + half * 8;
#pragma unroll
        for (int r = 0; r < 8; ++r) {
            Xs[(o0 + r) * 64 + lane] = yreg[half][r];
            stage[(o0 + r) * 256 + k0 + lane] = yreg[half][r];
        }
    }
    __syncthreads();

    // ================= m4 / seed =================
    {
        int o0 = wave * 8;   // rows 0..63
        float acc[8];
#pragma unroll
        for (int r = 0; r < 8; ++r) acc[r] = P.m4_b1[o0 + r];
        gemm8(P.m4_w1, 128, o0, Xs, 128, acc, lane);
#pragma unroll
        for (int r = 0; r < 8; ++r) Hs[(o0 + r) * 64 + lane] = fmaxf(acc[r], 0.f);
    }
    __syncthreads();
    if (wave < 3) {   // seed[b][d][k] = sum_j w2[d][j] * h4[j] + b2[d]
        int d = wave;
        float s = P.m4_b2[d];
        for (int j = 0; j < 64; ++j)
            s = fmaf(Hs[j * 64 + lane], P.m4_w2[d * 64 + j], s);
        fout[b * 768 + d * 256 + k0 + lane] = s;
    }
}

// ---------------------------------------------------------------------------
// k_fps: one block per batch; 4352 pts = 256 seed (f32, from d_out) + 4096
// partial. 511 sequential argmax iterations; f32 distances, no fma
// contraction (matches numpy's x^2+y^2 then +z^2); tie -> smallest index.
// ---------------------------------------------------------------------------
__global__ void __launch_bounds__(512)
k_fps(const float* __restrict__ seed, const float* __restrict__ partial,
      float* __restrict__ outx) {
    int b = blockIdx.x;
    int tid = threadIdx.x;
    float px[9], py[9], pz[9], dist[9];
#pragma unroll
    for (int s = 0; s < 9; ++s) {
        int gidx = tid + s * 512;
        bool valid = (gidx < 4352);
        float x = 0.f, y = 0.f, z = 0.f;
        if (valid) {
            if (gidx < 256) {            // seed [b][3][256]
                int base = b * 768 + gidx;
                x = seed[base]; y = seed[base + 256]; z = seed[base + 512];
            } else {                     // partial [b][4096][3]
                int base = (b * 4096 + (gidx - 256)) * 3;
                x = partial[base]; y = partial[base + 1]; z = partial[base + 2];
            }
        }
        px[s] = x; py[s] = y; pz[s] = z;
        dist[s] = valid ? 1e10f : -1.0f;
    }
    float cx = seed[b * 768], cy = seed[b * 768 + 256], cz = seed[b * 768 + 512];

    __shared__ float cvv[2][8], cxx[2][8], cyy[2][8], czz[2][8];
    __shared__ int cii[2][8];
    __shared__ int fars[512];
    if (tid == 0) fars[0] = 0;
    int bufc = 0;

    for (int t = 0; t < 511; ++t) {
        float bv = -2.0f; int bi = 0;
        float bx = 0.f, by = 0.f, bz = 0.f;
#pragma unroll
        for (int s = 0; s < 9; ++s) {
            float dx = px[s] - cx, dy = py[s] - cy, dz = pz[s] - cz;
            float d = __fadd_rn(__fadd_rn(__fmul_rn(dx, dx), __fmul_rn(dy, dy)),
                                __fmul_rn(dz, dz));
            dist[s] = fminf(dist[s], d);
            if (dist[s] > bv) { bv = dist[s]; bi = tid + s * 512;
                                bx = px[s]; by = py[s]; bz = pz[s]; }
        }
        // wave-64 butterfly: max val, tie -> min index
#pragma unroll
        for (int off = 32; off >= 1; off >>= 1) {
            float ov = __shfl_xor(bv, off, 64);
            int   oi = __shfl_xor(bi, off, 64);
            float ox = __shfl_xor(bx, off, 64);
            float oy = __shfl_xor(by, off, 64);
            float oz = __shfl_xor(bz, off, 64);
            bool take = (ov > bv) || (ov == bv && oi < bi);
            if (take) { bv = ov; bi = oi; bx = ox; by = oy; bz = oz; }
        }
        int wv = tid >> 6;
        if ((tid & 63) == 0) {
            cvv[bufc][wv] = bv; cii[bufc][wv] = bi;
            cxx[bufc][wv] = bx; cyy[bufc][wv] = by; czz[bufc][wv] = bz;
        }
        __syncthreads();
        bv = cvv[bufc][0]; bi = cii[bufc][0];
        bx = cxx[bufc][0]; by = cyy[bufc][0]; bz = czz[bufc][0];
#pragma unroll
        for (int w = 1; w < 8; ++w) {
            float ov = cvv[bufc][w]; int oi = cii[bufc][w];
            bool take = (ov > bv) || (ov == bv && oi < bi);
            if (take) { bv = ov; bi = oi; bx = cxx[bufc][w]; by = cyy[bufc][w]; bz = czz[bufc][w]; }
        }
        if (tid == 0) fars[t + 1] = bi;
        cx = bx; cy = by; cz = bz;
        bufc ^= 1;
    }
    __syncthreads();
    {
        int idx = fars[tid];
        float x, y, z;
        if (idx < 256) {
            int base = b * 768 + idx;
            x = seed[base]; y = seed[base + 256]; z = seed[base + 512];
        } else {
            int base = (b * 4096 + (idx - 256)) * 3;
            x = partial[base]; y = partial[base + 1]; z = partial[base + 2];
        }
        int ob = b * 1536 + tid;
        outx[ob] = x; outx[ob + 512] = y; outx[ob + 1024] = z;
    }
}

// ---------------------------------------------------------------------------
extern "C" void kernel_launch(void* const* d_in, const int* in_sizes, int n_in,
                              void* d_out, int out_size, void* d_ws, size_t ws_size,
                              hipStream_t stream) {
    (void)in_sizes; (void)n_in; (void)out_size; (void)ws_size;
    const float* feat    = (const float*)d_in[0];
    const float* partial = (const float*)d_in[3];
    const float* psw     = (const float*)d_in[4];
    const float* psb     = (const float*)d_in[5];

    FusedW P;
    P.m1_w1 = (const float*)d_in[6];  P.m1_b1 = (const float*)d_in[7];
    P.m1_w2 = (const float*)d_in[8];  P.m1_b2 = (const float*)d_in[9];
    P.m1_ws = (const float*)d_in[10]; P.m1_bs = (const float*)d_in[11];
    P.m2_w1 = (const float*)d_in[12]; P.m2_b1 = (const float*)d_in[13];
    P.m2_w2 = (const float*)d_in[14]; P.m2_b2 = (const float*)d_in[15];
    P.m2_ws = (const float*)d_in[16]; P.m2_bs = (const float*)d_in[17];
    P.m3_w1 = (const float*)d_in[18]; P.m3_b1 = (const float*)d_in[19];
    P.m3_w2 = (const float*)d_in[20]; P.m3_b2 = (const float*)d_in[21];
    P.m3_ws = (const float*)d_in[22]; P.m3_bs = (const float*)d_in[23];
    P.m4_w1 = (const float*)d_in[24]; P.m4_b1 = (const float*)d_in[25];
    P.m4_w2 = (const float*)d_in[26]; P.m4_b2 = (const float*)d_in[27];

    float* W = (float*)d_ws;
    float* out = (float*)d_out;

    k_prep<<<dim3(128), dim3(256), 0, stream>>>(feat, W);
    k_tterms<<<dim3(128), dim3(256), 0, stream>>>(P.m1_w1, P.m1_ws, P.m3_w1, P.m3_ws, W);
    k_deconv<<<dim3(128, 4), dim3(256), 0, stream>>>(psw, psb, W, out + X3_OFF);
    k_fused<<<dim3(256), dim3(512), 0, stream>>>(P, W, out);
    k_fps<<<dim3(64), dim3(512), 0, stream>>>(out, partial, out + FPS_OFF);
}

// Round 6
// 818.085 us; speedup vs baseline: 1.5743x; 1.5743x over previous
//
#include <hip/hip_runtime.h>
#include <stdint.h>

// d_out (f32) layout: seed [64][3][256] @0, x3 [64][128][256] @49152,
// fps x [64][3][512] @2146304.  x3 region doubles as x1 staging.
#define X3_OFF 49152
#define FPS_OFF 2146304

// ws (f32) layout: T1 @0, T1s @8192, T3 @16384, T3s @24576 (each [128][64]),
// featT [512][64] @32768.  Total 65536 floats = 256 KB.

// ---------------------------------------------------------------------------
// k_prep: featT[c][b] = feat[b][c]
// ---------------------------------------------------------------------------
__global__ void k_prep(const float* __restrict__ feat, float* __restrict__ ws) {
    int g = blockIdx.x * 256 + threadIdx.x;   // 32768
    int c = g >> 6, b = g & 63;
    ws[32768 + c * 64 + b] = feat[b * 512 + c];
}

// ---------------------------------------------------------------------------
// k_tterms: T[o][b] = sum_c W[o][128+c] * feat[b][c] for the 4 concat weights
// ---------------------------------------------------------------------------
__global__ void k_tterms(const float* __restrict__ w1, const float* __restrict__ ws1,
                         const float* __restrict__ w3, const float* __restrict__ ws3,
                         float* __restrict__ ws) {
    int g = blockIdx.x * 256 + threadIdx.x;   // 32768
    int which = g >> 13;
    int o = (g >> 6) & 127;
    int b = g & 63;
    const float* W = (which == 0) ? w1 : (which == 1) ? ws1
                     : (which == 2) ? w3 : ws3;
    const float* ft = ws + 32768;
    float acc = 0.f;
    for (int c = 0; c < 512; ++c)
        acc = fmaf(W[o * 640 + 128 + c], ft[c * 64 + b], acc);
    ws[which * 8192 + o * 64 + b] = acc;
}

// ---------------------------------------------------------------------------
// k_deconv: x1[b][o][k] = sum_c feat[b][c]*ps_w[c][o][k] + ps_b[o]
// written f32 into the d_out x3 region (staging; later overwritten with x3).
// ---------------------------------------------------------------------------
__global__ void k_deconv(const float* __restrict__ psw,
                         const float* __restrict__ psb,
                         const float* __restrict__ ws,
                         float* __restrict__ stage) {
    int n = blockIdx.x * 256 + threadIdx.x;   // 32768 = o*256+k
    int b0 = blockIdx.y * 16;
    const float* featT = ws + 32768;
    float acc[16];
    float bias = psb[n >> 8];
#pragma unroll
    for (int j = 0; j < 16; ++j) acc[j] = bias;
    for (int c = 0; c < 512; ++c) {
        float pw = psw[c * 32768 + n];
#pragma unroll
        for (int j = 0; j < 16; ++j)
            acc[j] = fmaf(pw, featT[c * 64 + b0 + j], acc[j]);
    }
#pragma unroll
    for (int j = 0; j < 16; ++j)
        stage[(b0 + j) * 32768 + n] = acc[j];
}

// ---------------------------------------------------------------------------
// gemm8: acc[r] += sum_i S[i][lane] * Wg[(o0+r)*ld + i]  (o0 wave-uniform)
// ---------------------------------------------------------------------------
__device__ __forceinline__ void gemm8(const float* __restrict__ Wg, int ld, int o0,
                                      const float* S, int K, float acc[8], int lane) {
#pragma unroll 4
    for (int i = 0; i < K; ++i) {
        float x = S[i * 64 + lane];
#pragma unroll
        for (int r = 0; r < 8; ++r)
            acc[r] = fmaf(x, Wg[(o0 + r) * ld + i], acc[r]);
    }
}

// ---------------------------------------------------------------------------
// k_fused: per (b, 64-wide k-tile): x1 -> m1 -> m2 -> m3 -> m4/seed.
// ---------------------------------------------------------------------------
struct FusedW {
    const float *m1_w1, *m1_b1, *m1_w2, *m1_b2, *m1_ws, *m1_bs;
    const float *m2_w1, *m2_b1, *m2_w2, *m2_b2, *m2_ws, *m2_bs;
    const float *m3_w1, *m3_b1, *m3_w2, *m3_b2, *m3_ws, *m3_bs;
    const float *m4_w1, *m4_b1, *m4_w2, *m4_b2;
};

__global__ void __launch_bounds__(512)
k_fused(FusedW P, const float* __restrict__ ws, float* __restrict__ fout) {
    int b  = blockIdx.x >> 2;
    int k0 = (blockIdx.x & 3) * 64;
    int lane = threadIdx.x & 63;
    int wave = __builtin_amdgcn_readfirstlane(threadIdx.x >> 6);

    const float* T1  = ws;
    const float* T1s = ws + 8192;
    const float* T3  = ws + 16384;
    const float* T3s = ws + 24576;
    float* stage = fout + X3_OFF + b * 32768;

    __shared__ float Xs[8192];
    __shared__ float Hs[8192];

#pragma unroll
    for (int s = 0; s < 16; ++s) {
        int e = threadIdx.x + s * 512;
        int o = e >> 6, kk = e & 63;
        Xs[e] = stage[o * 256 + k0 + kk];
    }
    __syncthreads();

    float yreg[2][8];

    // ================= m1 =================
#pragma unroll
    for (int half = 0; half < 2; ++half) {
        int o0 = wave * 16 + half * 8;
        float acc[8];
#pragma unroll
        for (int r = 0; r < 8; ++r) acc[r] = T1[(o0 + r) * 64 + b] + P.m1_b1[o0 + r];
        gemm8(P.m1_w1, 640, o0, Xs, 128, acc, lane);
#pragma unroll
        for (int r = 0; r < 8; ++r) Hs[(o0 + r) * 64 + lane] = fmaxf(acc[r], 0.f);
    }
    __syncthreads();
#pragma unroll
    for (int half = 0; half < 2; ++half) {
        int o0 = wave * 16 + half * 8;
        float acc[8];
#pragma unroll
        for (int r = 0; r < 8; ++r)
            acc[r] = T1s[(o0 + r) * 64 + b] + P.m1_b2[o0 + r] + P.m1_bs[o0 + r];
        gemm8(P.m1_w2, 128, o0, Hs, 128, acc, lane);
        gemm8(P.m1_ws, 640, o0, Xs, 128, acc, lane);
#pragma unroll
        for (int r = 0; r < 8; ++r) yreg[half][r] = acc[r];
    }
    __syncthreads();
#pragma unroll
    for (int half = 0; half < 2; ++half) {
        int o0 = wave * 16 + half * 8;
#pragma unroll
        for (int r = 0; r < 8; ++r) Xs[(o0 + r) * 64 + lane] = yreg[half][r];
    }
    __syncthreads();

    // ================= m2 =================
    {
        int o0 = wave * 8;
        float acc[8];
#pragma unroll
        for (int r = 0; r < 8; ++r) acc[r] = P.m2_b1[o0 + r];
        gemm8(P.m2_w1, 128, o0, Xs, 128, acc, lane);
#pragma unroll
        for (int r = 0; r < 8; ++r) Hs[(o0 + r) * 64 + lane] = fmaxf(acc[r], 0.f);
    }
    __syncthreads();
#pragma unroll
    for (int half = 0; half < 2; ++half) {
        int o0 = wave * 16 + half * 8;
        float acc[8];
#pragma unroll
        for (int r = 0; r < 8; ++r) acc[r] = P.m2_b2[o0 + r] + P.m2_bs[o0 + r];
        gemm8(P.m2_w2, 64, o0, Hs, 64, acc, lane);
        gemm8(P.m2_ws, 128, o0, Xs, 128, acc, lane);
#pragma unroll
        for (int r = 0; r < 8; ++r) yreg[half][r] = acc[r];
    }
    __syncthreads();
#pragma unroll
    for (int half = 0; half < 2; ++half) {
        int o0 = wave * 16 + half * 8;
#pragma unroll
        for (int r = 0; r < 8; ++r) Xs[(o0 + r) * 64 + lane] = yreg[half][r];
    }
    __syncthreads();

    // ================= m3 =================
#pragma unroll
    for (int half = 0; half < 2; ++half) {
        int o0 = wave * 16 + half * 8;
        float acc[8];
#pragma unroll
        for (int r = 0; r < 8; ++r) acc[r] = T3[(o0 + r) * 64 + b] + P.m3_b1[o0 + r];
        gemm8(P.m3_w1, 640, o0, Xs, 128, acc, lane);
#pragma unroll
        for (int r = 0; r < 8; ++r) Hs[(o0 + r) * 64 + lane] = fmaxf(acc[r], 0.f);
    }
    __syncthreads();
#pragma unroll
    for (int half = 0; half < 2; ++half) {
        int o0 = wave * 16 + half * 8;
        float acc[8];
#pragma unroll
        for (int r = 0; r < 8; ++r)
            acc[r] = T3s[(o0 + r) * 64 + b] + P.m3_b2[o0 + r] + P.m3_bs[o0 + r];
        gemm8(P.m3_w2, 128, o0, Hs, 128, acc, lane);
        gemm8(P.m3_ws, 640, o0, Xs, 128, acc, lane);
#pragma unroll
        for (int r = 0; r < 8; ++r) yreg[half][r] = acc[r];
    }
    __syncthreads();
#pragma unroll
    for (int half = 0; half < 2; ++half) {
        int o0 = wave * 16 + half * 8;
#pragma unroll
        for (int r = 0; r < 8; ++r) {
            Xs[(o0 + r) * 64 + lane] = yreg[half][r];
            stage[(o0 + r) * 256 + k0 + lane] = yreg[half][r];
        }
    }
    __syncthreads();

    // ================= m4 / seed =================
    {
        int o0 = wave * 8;
        float acc[8];
#pragma unroll
        for (int r = 0; r < 8; ++r) acc[r] = P.m4_b1[o0 + r];
        gemm8(P.m4_w1, 128, o0, Xs, 128, acc, lane);
#pragma unroll
        for (int r = 0; r < 8; ++r) Hs[(o0 + r) * 64 + lane] = fmaxf(acc[r], 0.f);
    }
    __syncthreads();
    if (wave < 3) {
        int d = wave;
        float s = P.m4_b2[d];
        for (int j = 0; j < 64; ++j)
            s = fmaf(Hs[j * 64 + lane], P.m4_w2[d * 64 + j], s);
        fout[b * 768 + d * 256 + k0 + lane] = s;
    }
}

// ---------------------------------------------------------------------------
// k_fps (v2): one block of 256 threads per batch; 4352 pts = 256*17 exactly.
// Points live both in registers (for dist update) and LDS (for centroid
// broadcast + output gather). Reduction payload = single u64
// (dist_bits<<13 | (8191-gidx)): max => max dist, tie -> min index.
// One barrier per iteration; ping-pong candidate slots.
// ---------------------------------------------------------------------------
__global__ void __launch_bounds__(256)
k_fps(const float* __restrict__ seed, const float* __restrict__ partial,
      float* __restrict__ outx) {
    int b = blockIdx.x;
    int tid = threadIdx.x;        // 0..255
    int lane = tid & 63;
    int wv = tid >> 6;            // 0..3

    __shared__ float pts[4352 * 3];          // [idx][3]
    __shared__ unsigned long long cand[2][4];
    __shared__ int fars[512];

    // stage seed [b][3][256] -> pts[idx<256]
#pragma unroll
    for (int d = 0; d < 3; ++d)
        pts[tid * 3 + d] = seed[b * 768 + d * 256 + tid];
    // stage partial [b][4096][3] -> pts[256..4351]  (linear 12288 dwords)
#pragma unroll
    for (int j = 0; j < 48; ++j) {
        int e = tid + j * 256;
        pts[768 + e] = partial[b * 12288 + e];
    }
    if (tid == 0) fars[0] = 0;
    __syncthreads();

    float px[17], py[17], pz[17], dist[17];
#pragma unroll
    for (int s = 0; s < 17; ++s) {
        int g = s * 256 + tid;
        px[s] = pts[g * 3 + 0];
        py[s] = pts[g * 3 + 1];
        pz[s] = pts[g * 3 + 2];
        dist[s] = 1e10f;
    }
    float cx = pts[0], cy = pts[1], cz = pts[2];

    for (int t = 0; t < 511; ++t) {
        // update running min-dist; track local best (max dist, min gidx)
        float bv = -1.0f; int bg = 0;
#pragma unroll
        for (int s = 0; s < 17; ++s) {
            float dx = px[s] - cx, dy = py[s] - cy, dz = pz[s] - cz;
            float d = __fadd_rn(__fadd_rn(__fmul_rn(dx, dx), __fmul_rn(dy, dy)),
                                __fmul_rn(dz, dz));
            dist[s] = fminf(dist[s], d);
            if (dist[s] > bv) { bv = dist[s]; bg = s * 256 + tid; }
        }
        unsigned long long U =
            (((unsigned long long)__float_as_uint(bv)) << 13) |
            (unsigned long long)(8191 - bg);

        // wave-64 butterfly max on packed u64
#pragma unroll
        for (int off = 32; off >= 1; off >>= 1) {
            unsigned long long oU =
                (unsigned long long)__shfl_xor((long long)U, off, 64);
            if (oU > U) U = oU;
        }
        if (lane == 0) cand[t & 1][wv] = U;
        __syncthreads();
        unsigned long long U0 = cand[t & 1][0];
        unsigned long long U1 = cand[t & 1][1];
        unsigned long long U2 = cand[t & 1][2];
        unsigned long long U3 = cand[t & 1][3];
        if (U1 > U0) U0 = U1;
        if (U3 > U2) U2 = U3;
        if (U2 > U0) U0 = U2;
        int bi = 8191 - (int)(U0 & 8191ull);
        cx = pts[bi * 3 + 0]; cy = pts[bi * 3 + 1]; cz = pts[bi * 3 + 2];
        if (tid == 0) fars[t + 1] = bi;
    }
    __syncthreads();

    // gather outputs: x [b][3][512]
#pragma unroll
    for (int j = 0; j < 2; ++j) {
        int n = tid + j * 256;
        int idx = fars[n];
        int ob = b * 1536 + n;
        outx[ob]        = pts[idx * 3 + 0];
        outx[ob + 512]  = pts[idx * 3 + 1];
        outx[ob + 1024] = pts[idx * 3 + 2];
    }
}

// ---------------------------------------------------------------------------
extern "C" void kernel_launch(void* const* d_in, const int* in_sizes, int n_in,
                              void* d_out, int out_size, void* d_ws, size_t ws_size,
                              hipStream_t stream) {
    (void)in_sizes; (void)n_in; (void)out_size; (void)ws_size;
    const float* feat    = (const float*)d_in[0];
    const float* partial = (const float*)d_in[3];
    const float* psw     = (const float*)d_in[4];
    const float* psb     = (const float*)d_in[5];

    FusedW P;
    P.m1_w1 = (const float*)d_in[6];  P.m1_b1 = (const float*)d_in[7];
    P.m1_w2 = (const float*)d_in[8];  P.m1_b2 = (const float*)d_in[9];
    P.m1_ws = (const float*)d_in[10]; P.m1_bs = (const float*)d_in[11];
    P.m2_w1 = (const float*)d_in[12]; P.m2_b1 = (const float*)d_in[13];
    P.m2_w2 = (const float*)d_in[14]; P.m2_b2 = (const float*)d_in[15];
    P.m2_ws = (const float*)d_in[16]; P.m2_bs = (const float*)d_in[17];
    P.m3_w1 = (const float*)d_in[18]; P.m3_b1 = (const float*)d_in[19];
    P.m3_w2 = (const float*)d_in[20]; P.m3_b2 = (const float*)d_in[21];
    P.m3_ws = (const float*)d_in[22]; P.m3_bs = (const float*)d_in[23];
    P.m4_w1 = (const float*)d_in[24]; P.m4_b1 = (const float*)d_in[25];
    P.m4_w2 = (const float*)d_in[26]; P.m4_b2 = (const float*)d_in[27];

    float* W = (float*)d_ws;
    float* out = (float*)d_out;

    k_prep<<<dim3(128), dim3(256), 0, stream>>>(feat, W);
    k_tterms<<<dim3(128), dim3(256), 0, stream>>>(P.m1_w1, P.m1_ws, P.m3_w1, P.m3_ws, W);
    k_deconv<<<dim3(128, 4), dim3(256), 0, stream>>>(psw, psb, W, out + X3_OFF);
    k_fused<<<dim3(256), dim3(512), 0, stream>>>(P, W, out);
    k_fps<<<dim3(64), dim3(256), 0, stream>>>(out, partial, out + FPS_OFF);
}